// Round 1
// baseline (495.139 us; speedup 1.0000x reference)
//
#include <hip/hip_runtime.h>

#define N_NODES 100000
#define N_EDGES 1250000
#define N_FEAT 128
#define NHID 64
#define NUM_GRAPHS 256

// ---------------------------------------------------------------------------
// K0: deg = 1.0 (self-loop weight), pooled = 0
// ---------------------------------------------------------------------------
__global__ void k0_init(float* __restrict__ deg, float* __restrict__ pooled) {
    int i = blockIdx.x * blockDim.x + threadIdx.x;
    if (i < N_NODES) deg[i] = 1.0f;
    if (i < NUM_GRAPHS * NHID) pooled[i] = 0.0f;
}

// ---------------------------------------------------------------------------
// K1: edge MLP -> edge_w[e] = relu(relu(relu(ea@W1+b1)@W2+b2)@W3+b3)
//     fused: atomicAdd(deg[col], w) for w > 0
// One thread per edge. All weight accesses are uniform -> s_load + SGPR fmac.
// ---------------------------------------------------------------------------
__global__ __launch_bounds__(256) void k1_edge_mlp(
    const float* __restrict__ ea, const float* __restrict__ W1,
    const float* __restrict__ b1, const float* __restrict__ W2,
    const float* __restrict__ b2, const float* __restrict__ W3,
    const float* __restrict__ b3, const int* __restrict__ eidx,
    float* __restrict__ edge_w, float* __restrict__ deg) {
    int e = blockIdx.x * 256 + threadIdx.x;
    if (e >= N_EDGES) return;

    float a[5];
    #pragma unroll
    for (int k = 0; k < 5; ++k) a[k] = ea[e * 5 + k];

    float h1[NHID];
    #pragma unroll
    for (int j = 0; j < NHID; ++j) {
        float t = b1[j];
        #pragma unroll
        for (int k = 0; k < 5; ++k) t += a[k] * W1[k * NHID + j];
        h1[j] = fmaxf(t, 0.0f);
    }

    float h2[NHID];
    #pragma unroll
    for (int j = 0; j < NHID; ++j) h2[j] = b2[j];
    #pragma unroll
    for (int k = 0; k < NHID; ++k) {
        float hk = h1[k];
        #pragma unroll
        for (int j = 0; j < NHID; ++j) h2[j] += hk * W2[k * NHID + j];
    }

    float w = b3[0];
    #pragma unroll
    for (int j = 0; j < NHID; ++j) w += fmaxf(h2[j], 0.0f) * W3[j];
    w = fmaxf(w, 0.0f);

    edge_w[e] = w;
    if (w > 0.0f) {
        int col = eidx[N_EDGES + e];
        atomicAdd(&deg[col], w);
    }
}

// ---------------------------------------------------------------------------
// K2: dinv = rsqrt(deg)  (deg >= 1 always, self-loop guarantees it)
// ---------------------------------------------------------------------------
__global__ void k2_rsqrt(float* __restrict__ deg) {
    int i = blockIdx.x * blockDim.x + threadIdx.x;
    if (i < N_NODES) deg[i] = rsqrtf(deg[i]);
}

// ---------------------------------------------------------------------------
// K3: xws[n] = dinv[n] * (x[n] @ W_g); agg init = xws (self-loop term).
// Block = 256 threads = 4 waves; each wave does 4 nodes, lane = out feature.
// W_g staged in LDS (32 KB); x row values are wave-uniform -> s_load.
// ---------------------------------------------------------------------------
__global__ __launch_bounds__(256) void k3_xw(
    const float* __restrict__ x, const float* __restrict__ Wg,
    const float* __restrict__ dinv, float* __restrict__ xws,
    float* __restrict__ agg) {
    __shared__ float lds[N_FEAT * NHID];
    int t = threadIdx.x;
    #pragma unroll
    for (int i = 0; i < (N_FEAT * NHID) / 256; ++i)
        lds[t + i * 256] = Wg[t + i * 256];
    __syncthreads();

    int lane = t & 63;
    int wid = __builtin_amdgcn_readfirstlane(t >> 6);
    int n0 = blockIdx.x * 16 + wid * 4;

    float acc[4] = {0.f, 0.f, 0.f, 0.f};
    #pragma unroll 8
    for (int k = 0; k < N_FEAT; ++k) {
        float wv = lds[k * NHID + lane];
        #pragma unroll
        for (int nn = 0; nn < 4; ++nn)
            acc[nn] += x[(n0 + nn) * N_FEAT + k] * wv;
    }

    #pragma unroll
    for (int nn = 0; nn < 4; ++nn) {
        int n = n0 + nn;
        float v = acc[nn] * dinv[n];
        xws[n * NHID + lane] = v;
        agg[n * NHID + lane] = v;
    }
}

// ---------------------------------------------------------------------------
// K4: agg[col] += w_e * xws[row].  One wave per edge, lane = feature.
// Skips dead edges (w == 0, ~half after ReLU) with a wave-uniform branch.
// ---------------------------------------------------------------------------
__global__ __launch_bounds__(256) void k4_scatter(
    const float* __restrict__ edge_w, const int* __restrict__ eidx,
    const float* __restrict__ xws, float* __restrict__ agg) {
    int lane = threadIdx.x & 63;
    int wid = __builtin_amdgcn_readfirstlane(threadIdx.x >> 6);
    int e = blockIdx.x * 4 + wid;
    if (e >= N_EDGES) return;
    float w = edge_w[e];
    if (w <= 0.0f) return;
    int row = eidx[e];
    int col = eidx[N_EDGES + e];
    float v = w * xws[row * NHID + lane];
    atomicAdd(&agg[col * NHID + lane], v);
}

// ---------------------------------------------------------------------------
// K5: node = relu(dinv[n]*agg[n] + b_g); pooled[batch[n]] += node.
// batch is sorted: one wave per 256-node chunk, running per-graph accumulator,
// flush (atomic) only on graph-id change.
// ---------------------------------------------------------------------------
__global__ __launch_bounds__(64) void k5_pool(
    const float* __restrict__ agg, const float* __restrict__ dinv,
    const float* __restrict__ bg, const int* __restrict__ batch,
    float* __restrict__ pooled) {
    int lane = threadIdx.x;
    int n0 = blockIdx.x * 256;
    int n1 = min(n0 + 256, N_NODES);
    if (n0 >= N_NODES) return;
    float bgl = bg[lane];
    float acc = 0.0f;
    int cur = batch[n0];
    for (int n = n0; n < n1; ++n) {
        int g = batch[n];
        if (g != cur) {
            atomicAdd(&pooled[cur * NHID + lane], acc);
            acc = 0.0f;
            cur = g;
        }
        float v = fmaxf(dinv[n] * agg[n * NHID + lane] + bgl, 0.0f);
        acc += v;
    }
    atomicAdd(&pooled[cur * NHID + lane], acc);
}

// ---------------------------------------------------------------------------
// K6: z = relu(pooled @ W_b1 + b_b1); out = z @ W_b2 + b_b2.
// One 64-thread block per graph.
// ---------------------------------------------------------------------------
__global__ __launch_bounds__(64) void k6_final(
    const float* __restrict__ pooled, const float* __restrict__ Wb1,
    const float* __restrict__ bb1, const float* __restrict__ Wb2,
    const float* __restrict__ bb2, float* __restrict__ out) {
    __shared__ float p[NHID];
    int lane = threadIdx.x;
    int g = blockIdx.x;
    p[lane] = pooled[g * NHID + lane];
    __syncthreads();
    float z = bb1[lane];
    #pragma unroll
    for (int k = 0; k < NHID; ++k) z += p[k] * Wb1[k * NHID + lane];
    z = fmaxf(z, 0.0f) * Wb2[lane];
    #pragma unroll
    for (int off = 32; off > 0; off >>= 1)
        z += __shfl_down(z, off, 64);
    if (lane == 0) out[g] = z + bb2[0];
}

// ---------------------------------------------------------------------------
extern "C" void kernel_launch(void* const* d_in, const int* in_sizes, int n_in,
                              void* d_out, int out_size, void* d_ws, size_t ws_size,
                              hipStream_t stream) {
    const float* x        = (const float*)d_in[0];
    const float* ea       = (const float*)d_in[1];
    const float* W_e1     = (const float*)d_in[2];
    const float* b_e1     = (const float*)d_in[3];
    const float* W_e2     = (const float*)d_in[4];
    const float* b_e2     = (const float*)d_in[5];
    const float* W_e3     = (const float*)d_in[6];
    const float* b_e3     = (const float*)d_in[7];
    const float* W_g      = (const float*)d_in[8];
    const float* b_g      = (const float*)d_in[9];
    const float* W_b1     = (const float*)d_in[10];
    const float* b_b1     = (const float*)d_in[11];
    const float* W_b2     = (const float*)d_in[12];
    const float* b_b2     = (const float*)d_in[13];
    const int*   eidx     = (const int*)d_in[14];
    const int*   batch    = (const int*)d_in[15];
    float* out = (float*)d_out;

    // workspace layout (floats), 256B-aligned offsets; total ~56.7 MB
    float* ws = (float*)d_ws;
    float* edge_w = ws;                         // 1,250,000
    float* deg    = ws + 1250048;               // 100,000 (becomes dinv in-place)
    float* xws    = ws + 1350080;               // 6,400,000
    float* agg    = ws + 7750080;               // 6,400,000
    float* pooled = ws + 14150080;              // 16,384

    k0_init<<<dim3((N_NODES + 255) / 256), dim3(256), 0, stream>>>(deg, pooled);
    k1_edge_mlp<<<dim3((N_EDGES + 255) / 256), dim3(256), 0, stream>>>(
        ea, W_e1, b_e1, W_e2, b_e2, W_e3, b_e3, eidx, edge_w, deg);
    k2_rsqrt<<<dim3((N_NODES + 255) / 256), dim3(256), 0, stream>>>(deg);
    k3_xw<<<dim3(N_NODES / 16), dim3(256), 0, stream>>>(x, W_g, deg, xws, agg);
    k4_scatter<<<dim3((N_EDGES + 3) / 4), dim3(256), 0, stream>>>(edge_w, eidx, xws, agg);
    k5_pool<<<dim3((N_NODES + 255) / 256), dim3(64), 0, stream>>>(agg, deg, b_g, batch, pooled);
    k6_final<<<dim3(NUM_GRAPHS), dim3(64), 0, stream>>>(pooled, W_b1, b_b1, W_b2, b_b2, out);
}

// Round 2
// 403.896 us; speedup vs baseline: 1.2259x; 1.2259x over previous
//
#include <hip/hip_runtime.h>
#include <hip/hip_bf16.h>

#define N_NODES 100000
#define N_EDGES 1250000
#define N_FEAT 128
#define NHID 64
#define NUM_GRAPHS 256

typedef __attribute__((ext_vector_type(8))) short short8;
typedef __attribute__((ext_vector_type(16))) float float16;

static __device__ __forceinline__ short f2bf(float x) {
    __hip_bfloat16 b = __float2bfloat16(x);
    return *reinterpret_cast<short*>(&b);
}

// ---------------------------------------------------------------------------
// K0: deg = 1.0 (self-loop weight), pooled = 0
// ---------------------------------------------------------------------------
__global__ void k0_init(float* __restrict__ deg, float* __restrict__ pooled) {
    int i = blockIdx.x * blockDim.x + threadIdx.x;
    if (i < N_NODES) deg[i] = 1.0f;
    if (i < NUM_GRAPHS * NHID) pooled[i] = 0.0f;
}

// ---------------------------------------------------------------------------
// K1: edge MLP via MFMA.  One wave per 32 edges (grid-stride).
// Layer1 (5->64): fp32 VALU, SGPR weights, each lane computes full h1 for
//   edge = lane&31 (redundant across halves — needed for the B-frag layout).
// Layer2 (64->64): h2T = W2T @ h1T with mfma_f32_32x32x16_bf16.
//   A = W2T (register-resident frags), B = h1T: lane holds
//   B[k=(lane>>5)*8+j][n=lane&31] = h1[edge=lane&31][k] -> built by cndmask.
//   C/D layout: col(lane&31) = EDGE, row = hid2 -> layer3 reduces in-register.
// Layer3 (64->1): per-lane partial over its 32 hid2 rows + one shfl_xor(32).
// Fused: edge_w store + atomicAdd(deg[col], w) on lanes<32.
// ---------------------------------------------------------------------------
__global__ __launch_bounds__(256) void k1_edge_mlp(
    const float* __restrict__ ea, const float* __restrict__ W1,
    const float* __restrict__ b1, const float* __restrict__ W2,
    const float* __restrict__ b2, const float* __restrict__ W3,
    const float* __restrict__ b3, const int* __restrict__ eidx,
    float* __restrict__ edge_w, float* __restrict__ deg)
{
    const int lane = threadIdx.x & 63;
    const int l31 = lane & 31;
    const int h = lane >> 5;                       // which half of the wave
    const int wslot = blockIdx.x * 4 + (threadIdx.x >> 6);   // 0..4095
    const float b3v = b3[0];

    // ---- preload W2T A-fragments: afrag[t][kk]
    // A[m = t*32 + (lane&31)][k = kk*16 + h*8 + j] = W2[k][t*32+l31]
    short8 afrag[2][4];
    #pragma unroll
    for (int t = 0; t < 2; ++t)
        #pragma unroll
        for (int kk = 0; kk < 4; ++kk)
            #pragma unroll
            for (int j = 0; j < 8; ++j) {
                int k = kk * 16 + h * 8 + j;
                afrag[t][kk][j] = f2bf(W2[k * NHID + t * 32 + l31]);
            }

    // ---- preload b2/W3 for this lane's C-layout rows
    // row(t, r) = t*32 + (r&3) + 8*(r>>2) + 4*h
    float b2r[2][16], w3r[2][16];
    #pragma unroll
    for (int t = 0; t < 2; ++t)
        #pragma unroll
        for (int r = 0; r < 16; ++r) {
            int hid = t * 32 + (r & 3) + 8 * (r >> 2) + 4 * h;
            b2r[t][r] = b2[hid];
            w3r[t][r] = W3[hid];
        }

    const int NCHUNK = (N_EDGES + 31) / 32;        // 39063
    for (int chunk = wslot; chunk < NCHUNK; chunk += 4096) {
        int e = chunk * 32 + l31;
        bool valid = e < N_EDGES;
        int ec = valid ? e : (N_EDGES - 1);

        float a0 = ea[ec * 5 + 0], a1 = ea[ec * 5 + 1], a2 = ea[ec * 5 + 2],
              a3 = ea[ec * 5 + 3], a4 = ea[ec * 5 + 4];

        // layer 1: full h1 per lane (W1/b1 wave-uniform -> s_load operands)
        float h1[NHID];
        #pragma unroll
        for (int jj = 0; jj < NHID; ++jj) {
            float t = b1[jj];
            t = fmaf(a0, W1[0 * NHID + jj], t);
            t = fmaf(a1, W1[1 * NHID + jj], t);
            t = fmaf(a2, W1[2 * NHID + jj], t);
            t = fmaf(a3, W1[3 * NHID + jj], t);
            t = fmaf(a4, W1[4 * NHID + jj], t);
            h1[jj] = fmaxf(t, 0.0f);
        }

        // B-frags: lane needs h1[kk*16 + 8*h + j]; h runtime -> cndmask select
        short8 bfrag[4];
        #pragma unroll
        for (int kk = 0; kk < 4; ++kk)
            #pragma unroll
            for (int j = 0; j < 8; ++j) {
                float v = h ? h1[kk * 16 + 8 + j] : h1[kk * 16 + j];
                bfrag[kk][j] = f2bf(v);
            }

        float16 acc0 = {0,0,0,0,0,0,0,0,0,0,0,0,0,0,0,0};
        float16 acc1 = {0,0,0,0,0,0,0,0,0,0,0,0,0,0,0,0};
        #pragma unroll
        for (int kk = 0; kk < 4; ++kk) {
            acc0 = __builtin_amdgcn_mfma_f32_32x32x16_bf16(afrag[0][kk], bfrag[kk], acc0, 0, 0, 0);
            acc1 = __builtin_amdgcn_mfma_f32_32x32x16_bf16(afrag[1][kk], bfrag[kk], acc1, 0, 0, 0);
        }

        // layer 3: edge_w = relu( sum_hid relu(h2+b2)*W3 + b3 )
        float partial = 0.0f;
        #pragma unroll
        for (int r = 0; r < 16; ++r) {
            partial += fmaxf(acc0[r] + b2r[0][r], 0.0f) * w3r[0][r];
            partial += fmaxf(acc1[r] + b2r[1][r], 0.0f) * w3r[1][r];
        }
        float total = partial + __shfl_xor(partial, 32, 64);
        float w = fmaxf(total + b3v, 0.0f);

        if (h == 0 && valid) {
            edge_w[e] = w;
            if (w > 0.0f) atomicAdd(&deg[eidx[N_EDGES + e]], w);
        }
    }
}

// ---------------------------------------------------------------------------
// K2: dinv = rsqrt(deg)  (deg >= 1 always, self-loop guarantees it)
// ---------------------------------------------------------------------------
__global__ void k2_rsqrt(float* __restrict__ deg) {
    int i = blockIdx.x * blockDim.x + threadIdx.x;
    if (i < N_NODES) deg[i] = rsqrtf(deg[i]);
}

// ---------------------------------------------------------------------------
// K3: xws[n] = dinv[n] * (x[n] @ W_g); agg init = xws (self-loop term).
// ---------------------------------------------------------------------------
__global__ __launch_bounds__(256) void k3_xw(
    const float* __restrict__ x, const float* __restrict__ Wg,
    const float* __restrict__ dinv, float* __restrict__ xws,
    float* __restrict__ agg) {
    __shared__ float lds[N_FEAT * NHID];
    int t = threadIdx.x;
    #pragma unroll
    for (int i = 0; i < (N_FEAT * NHID) / 256; ++i)
        lds[t + i * 256] = Wg[t + i * 256];
    __syncthreads();

    int lane = t & 63;
    int wid = __builtin_amdgcn_readfirstlane(t >> 6);
    int n0 = blockIdx.x * 16 + wid * 4;

    float acc[4] = {0.f, 0.f, 0.f, 0.f};
    #pragma unroll 8
    for (int k = 0; k < N_FEAT; ++k) {
        float wv = lds[k * NHID + lane];
        #pragma unroll
        for (int nn = 0; nn < 4; ++nn)
            acc[nn] += x[(n0 + nn) * N_FEAT + k] * wv;
    }

    #pragma unroll
    for (int nn = 0; nn < 4; ++nn) {
        int n = n0 + nn;
        float v = acc[nn] * dinv[n];
        xws[n * NHID + lane] = v;
        agg[n * NHID + lane] = v;
    }
}

// ---------------------------------------------------------------------------
// K4: agg[col] += w_e * xws[row].  One wave per edge, lane = feature.
// ---------------------------------------------------------------------------
__global__ __launch_bounds__(256) void k4_scatter(
    const float* __restrict__ edge_w, const int* __restrict__ eidx,
    const float* __restrict__ xws, float* __restrict__ agg) {
    int lane = threadIdx.x & 63;
    int wid = __builtin_amdgcn_readfirstlane(threadIdx.x >> 6);
    int e = blockIdx.x * 4 + wid;
    if (e >= N_EDGES) return;
    float w = edge_w[e];
    if (w <= 0.0f) return;
    int row = eidx[e];
    int col = eidx[N_EDGES + e];
    float v = w * xws[row * NHID + lane];
    atomicAdd(&agg[col * NHID + lane], v);
}

// ---------------------------------------------------------------------------
// K5: node = relu(dinv[n]*agg[n] + b_g); pooled[batch[n]] += node.
// One wave per 64 nodes (latency hiding via 1563 waves); batch sorted ->
// running accumulator, atomic flush only on graph-id change.
// ---------------------------------------------------------------------------
__global__ __launch_bounds__(64) void k5_pool(
    const float* __restrict__ agg, const float* __restrict__ dinv,
    const float* __restrict__ bg, const int* __restrict__ batch,
    float* __restrict__ pooled) {
    int lane = threadIdx.x;
    int n0 = blockIdx.x * 64;
    int n1 = min(n0 + 64, N_NODES);
    if (n0 >= N_NODES) return;
    float bgl = bg[lane];
    float acc = 0.0f;
    int cur = batch[n0];
    for (int n = n0; n < n1; ++n) {
        int g = batch[n];
        if (g != cur) {
            atomicAdd(&pooled[cur * NHID + lane], acc);
            acc = 0.0f;
            cur = g;
        }
        float v = fmaxf(dinv[n] * agg[n * NHID + lane] + bgl, 0.0f);
        acc += v;
    }
    atomicAdd(&pooled[cur * NHID + lane], acc);
}

// ---------------------------------------------------------------------------
// K6: z = relu(pooled @ W_b1 + b_b1); out = z @ W_b2 + b_b2.
// ---------------------------------------------------------------------------
__global__ __launch_bounds__(64) void k6_final(
    const float* __restrict__ pooled, const float* __restrict__ Wb1,
    const float* __restrict__ bb1, const float* __restrict__ Wb2,
    const float* __restrict__ bb2, float* __restrict__ out) {
    __shared__ float p[NHID];
    int lane = threadIdx.x;
    int g = blockIdx.x;
    p[lane] = pooled[g * NHID + lane];
    __syncthreads();
    float z = bb1[lane];
    #pragma unroll
    for (int k = 0; k < NHID; ++k) z += p[k] * Wb1[k * NHID + lane];
    z = fmaxf(z, 0.0f) * Wb2[lane];
    #pragma unroll
    for (int off = 32; off > 0; off >>= 1)
        z += __shfl_down(z, off, 64);
    if (lane == 0) out[g] = z + bb2[0];
}

// ---------------------------------------------------------------------------
extern "C" void kernel_launch(void* const* d_in, const int* in_sizes, int n_in,
                              void* d_out, int out_size, void* d_ws, size_t ws_size,
                              hipStream_t stream) {
    const float* x        = (const float*)d_in[0];
    const float* ea       = (const float*)d_in[1];
    const float* W_e1     = (const float*)d_in[2];
    const float* b_e1     = (const float*)d_in[3];
    const float* W_e2     = (const float*)d_in[4];
    const float* b_e2     = (const float*)d_in[5];
    const float* W_e3     = (const float*)d_in[6];
    const float* b_e3     = (const float*)d_in[7];
    const float* W_g      = (const float*)d_in[8];
    const float* b_g      = (const float*)d_in[9];
    const float* W_b1     = (const float*)d_in[10];
    const float* b_b1     = (const float*)d_in[11];
    const float* W_b2     = (const float*)d_in[12];
    const float* b_b2     = (const float*)d_in[13];
    const int*   eidx     = (const int*)d_in[14];
    const int*   batch    = (const int*)d_in[15];
    float* out = (float*)d_out;

    float* ws = (float*)d_ws;
    float* edge_w = ws;                         // 1,250,000
    float* deg    = ws + 1250048;               // 100,000 (becomes dinv in-place)
    float* xws    = ws + 1350080;               // 6,400,000
    float* agg    = ws + 7750080;               // 6,400,000
    float* pooled = ws + 14150080;              // 16,384

    k0_init<<<dim3((N_NODES + 255) / 256), dim3(256), 0, stream>>>(deg, pooled);
    k1_edge_mlp<<<dim3(1024), dim3(256), 0, stream>>>(
        ea, W_e1, b_e1, W_e2, b_e2, W_e3, b_e3, eidx, edge_w, deg);
    k2_rsqrt<<<dim3((N_NODES + 255) / 256), dim3(256), 0, stream>>>(deg);
    k3_xw<<<dim3(N_NODES / 16), dim3(256), 0, stream>>>(x, W_g, deg, xws, agg);
    k4_scatter<<<dim3((N_EDGES + 3) / 4), dim3(256), 0, stream>>>(edge_w, eidx, xws, agg);
    k5_pool<<<dim3((N_NODES + 63) / 64), dim3(64), 0, stream>>>(agg, deg, b_g, batch, pooled);
    k6_final<<<dim3(NUM_GRAPHS), dim3(64), 0, stream>>>(pooled, W_b1, b_b1, W_b2, b_b2, out);
}

// Round 3
// 304.484 us; speedup vs baseline: 1.6262x; 1.3265x over previous
//
#include <hip/hip_runtime.h>
#include <hip/hip_bf16.h>

#define N_NODES 100000
#define N_EDGES 1250000
#define N_FEAT 128
#define NHID 64
#define NUM_GRAPHS 256

typedef __attribute__((ext_vector_type(8))) short short8;
typedef __attribute__((ext_vector_type(16))) float float16;

static __device__ __forceinline__ short f2bf(float x) {
    __hip_bfloat16 b = __float2bfloat16(x);
    return *reinterpret_cast<short*>(&b);
}
static __device__ __forceinline__ float bf2f(short s) {
    __hip_bfloat16 b = *reinterpret_cast<__hip_bfloat16*>(&s);
    return __bfloat162float(b);
}

// ---------------------------------------------------------------------------
// K0: deg = 1.0 (self-loop weight), pooled = 0
// ---------------------------------------------------------------------------
__global__ void k0_init(float* __restrict__ deg, float* __restrict__ pooled) {
    int i = blockIdx.x * blockDim.x + threadIdx.x;
    if (i < N_NODES) deg[i] = 1.0f;
    if (i < NUM_GRAPHS * NHID) pooled[i] = 0.0f;
}

// ---------------------------------------------------------------------------
// K1: edge MLP, all-MFMA. One wave per 32 edges (grid-stride).
// Layer1 (5->64): h1T = W1T@eaT via 32x32x16_bf16, hi/lo split (near-fp32):
//   A_hi*B_hi + A_hi*B_lo + A_lo*B_hi, 3 MFMAs per m-half; b1 in C-init.
// Exchange: layer1 C-layout (col=edge, row=hid; rows (r&3)+8(r>>2)+4h) ->
//   layer2 B-layout (k=kk*16+8h+j) needs the cross-half values: 16 shfl_xor(32).
// Layer2 (64->64): h2T = W2T@h1T, b2 in C-init.
// Layer3: per-lane partial over 32 hid2 rows + shfl_xor(32).
// ---------------------------------------------------------------------------
__global__ __launch_bounds__(256) void k1_edge_mlp(
    const float* __restrict__ ea, const float* __restrict__ W1,
    const float* __restrict__ b1, const float* __restrict__ W2,
    const float* __restrict__ b2, const float* __restrict__ W3,
    const float* __restrict__ b3, const int* __restrict__ eidx,
    float* __restrict__ edge_w, float* __restrict__ deg)
{
    const int lane = threadIdx.x & 63;
    const int l31 = lane & 31;
    const int h = lane >> 5;
    const int wslot = blockIdx.x * 4 + (threadIdx.x >> 6);
    const float b3v = b3[0];

    // ---- layer1 A-frags: W1^T hi/lo.  A[m=t*32+l31][k=8h+j] = W1[k][m], k<5.
    short8 a1hi[2], a1lo[2];
    #pragma unroll
    for (int t = 0; t < 2; ++t)
        #pragma unroll
        for (int j = 0; j < 8; ++j) {
            int k = 8 * h + j;
            float v = (k < 5) ? W1[k * NHID + t * 32 + l31] : 0.0f;
            short hi = f2bf(v);
            a1hi[t][j] = hi;
            a1lo[t][j] = f2bf(v - bf2f(hi));
        }

    // ---- b1 at layer1 C-layout rows: row(t,r,h) = t*32 + (r&3)+8*(r>>2)+4h
    float b1r[2][16];
    #pragma unroll
    for (int t = 0; t < 2; ++t)
        #pragma unroll
        for (int r = 0; r < 16; ++r)
            b1r[t][r] = b1[t * 32 + (r & 3) + 8 * (r >> 2) + 4 * h];

    // ---- layer2 A-frags: A[m=t*32+l31][k=kk*16+8h+j] = W2[k][m]
    short8 afrag[2][4];
    #pragma unroll
    for (int t = 0; t < 2; ++t)
        #pragma unroll
        for (int kk = 0; kk < 4; ++kk)
            #pragma unroll
            for (int j = 0; j < 8; ++j) {
                int k = kk * 16 + h * 8 + j;
                afrag[t][kk][j] = f2bf(W2[k * NHID + t * 32 + l31]);
            }

    // ---- b2 / W3 at layer2 C-layout rows
    float b2r[2][16], w3r[2][16];
    #pragma unroll
    for (int t = 0; t < 2; ++t)
        #pragma unroll
        for (int r = 0; r < 16; ++r) {
            int hid = t * 32 + (r & 3) + 8 * (r >> 2) + 4 * h;
            b2r[t][r] = b2[hid];
            w3r[t][r] = W3[hid];
        }

    const int NCHUNK = (N_EDGES + 31) / 32;        // 39063
    for (int chunk = wslot; chunk < NCHUNK; chunk += gridDim.x * 4) {
        int e = chunk * 32 + l31;
        bool valid = e < N_EDGES;
        int ec = valid ? e : (N_EDGES - 1);

        // ---- ea B-frags hi/lo: B[k=8h+j][n=l31]; nonzero only h==0, j<5
        short8 behi, belo;
        #pragma unroll
        for (int j = 0; j < 8; ++j) {
            float v = (h == 0 && j < 5) ? ea[ec * 5 + j] : 0.0f;
            short hi = f2bf(v);
            behi[j] = hi;
            belo[j] = f2bf(v - bf2f(hi));
        }

        // ---- layer1 MFMAs (C init = b1)
        float16 acc1a, acc1b;
        #pragma unroll
        for (int r = 0; r < 16; ++r) { acc1a[r] = b1r[0][r]; acc1b[r] = b1r[1][r]; }
        acc1a = __builtin_amdgcn_mfma_f32_32x32x16_bf16(a1hi[0], behi, acc1a, 0, 0, 0);
        acc1a = __builtin_amdgcn_mfma_f32_32x32x16_bf16(a1hi[0], belo, acc1a, 0, 0, 0);
        acc1a = __builtin_amdgcn_mfma_f32_32x32x16_bf16(a1lo[0], behi, acc1a, 0, 0, 0);
        acc1b = __builtin_amdgcn_mfma_f32_32x32x16_bf16(a1hi[1], behi, acc1b, 0, 0, 0);
        acc1b = __builtin_amdgcn_mfma_f32_32x32x16_bf16(a1hi[1], belo, acc1b, 0, 0, 0);
        acc1b = __builtin_amdgcn_mfma_f32_32x32x16_bf16(a1lo[1], behi, acc1b, 0, 0, 0);
        #pragma unroll
        for (int r = 0; r < 16; ++r) {
            acc1a[r] = fmaxf(acc1a[r], 0.0f);
            acc1b[r] = fmaxf(acc1b[r], 0.0f);
        }

        // ---- exchange + pack into layer2 B-frags
        // for lane (l31,h), kk, j: needs h1[kk*16+8h+j] = acc_{kk>>1} reg
        // (j&3)+8*(kk&1)+4h of phys-half (j>>2).
        short8 bf2v[4];
        #pragma unroll
        for (int kk = 0; kk < 4; ++kk) {
            #pragma unroll
            for (int j2 = 0; j2 < 4; ++j2) {
                float lv, hv;
                if (kk >> 1) { lv = acc1b[j2 + 8 * (kk & 1)]; hv = acc1b[j2 + 8 * (kk & 1) + 4]; }
                else         { lv = acc1a[j2 + 8 * (kk & 1)]; hv = acc1a[j2 + 8 * (kk & 1) + 4]; }
                float send = h ? lv : hv;
                float recv = __shfl_xor(send, 32, 64);
                float jlo = h ? recv : lv;   // value for j = j2
                float jhi = h ? hv : recv;   // value for j = 4+j2
                bf2v[kk][j2] = f2bf(jlo);
                bf2v[kk][4 + j2] = f2bf(jhi);
            }
        }

        // ---- layer2 MFMAs (C init = b2)
        float16 c0, c1;
        #pragma unroll
        for (int r = 0; r < 16; ++r) { c0[r] = b2r[0][r]; c1[r] = b2r[1][r]; }
        #pragma unroll
        for (int kk = 0; kk < 4; ++kk) {
            c0 = __builtin_amdgcn_mfma_f32_32x32x16_bf16(afrag[0][kk], bf2v[kk], c0, 0, 0, 0);
            c1 = __builtin_amdgcn_mfma_f32_32x32x16_bf16(afrag[1][kk], bf2v[kk], c1, 0, 0, 0);
        }

        // ---- layer3
        float partial = 0.0f;
        #pragma unroll
        for (int r = 0; r < 16; ++r) {
            partial += fmaxf(c0[r], 0.0f) * w3r[0][r];
            partial += fmaxf(c1[r], 0.0f) * w3r[1][r];
        }
        float total = partial + __shfl_xor(partial, 32, 64);
        float w = fmaxf(total + b3v, 0.0f);

        if (h == 0 && valid) {
            edge_w[e] = w;
            if (w > 0.0f) atomicAdd(&deg[eidx[N_EDGES + e]], w);
        }
    }
}

// ---------------------------------------------------------------------------
// K2: dinv = rsqrt(deg)
// ---------------------------------------------------------------------------
__global__ void k2_rsqrt(float* __restrict__ deg) {
    int i = blockIdx.x * blockDim.x + threadIdx.x;
    if (i < N_NODES) deg[i] = rsqrtf(deg[i]);
}

// ---------------------------------------------------------------------------
// K3: xws[n] = dinv[n]*(x[n]@Wg); agg init = xws.  MFMA: one wave per
// 32 nodes.  A = x tile (float4 loads -> bf16), B = Wg (register frags),
// D[m=node][n=hid] -> C-layout rows are nodes: stores are 128B-contiguous
// per half-wave.  16 MFMAs / 32 nodes; no LDS.
// ---------------------------------------------------------------------------
__global__ __launch_bounds__(256) void k3_xw(
    const float* __restrict__ x, const float* __restrict__ Wg,
    const float* __restrict__ dinv, float* __restrict__ xws,
    float* __restrict__ agg)
{
    const int lane = threadIdx.x & 63;
    const int l31 = lane & 31;
    const int h = lane >> 5;
    const int wslot = blockIdx.x * 4 + (threadIdx.x >> 6);

    // B-frags: B[k=kk*16+8h+j][n=u*32+l31] = Wg[k][u*32+l31]
    short8 bw[8][2];
    #pragma unroll
    for (int kk = 0; kk < 8; ++kk)
        #pragma unroll
        for (int u = 0; u < 2; ++u)
            #pragma unroll
            for (int j = 0; j < 8; ++j)
                bw[kk][u][j] = f2bf(Wg[(kk * 16 + 8 * h + j) * NHID + u * 32 + l31]);

    const int NC = N_NODES / 32;   // 3125 exactly
    for (int chunk = wslot; chunk < NC; chunk += gridDim.x * 4) {
        int base = chunk * 32;
        const float* xrow = x + (size_t)(base + l31) * N_FEAT + 8 * h;

        float16 acc0, acc1;
        #pragma unroll
        for (int r = 0; r < 16; ++r) { acc0[r] = 0.0f; acc1[r] = 0.0f; }

        #pragma unroll
        for (int kk = 0; kk < 8; ++kk) {
            float4 p = *(const float4*)(xrow + kk * 16);
            float4 q = *(const float4*)(xrow + kk * 16 + 4);
            short8 af;
            af[0] = f2bf(p.x); af[1] = f2bf(p.y); af[2] = f2bf(p.z); af[3] = f2bf(p.w);
            af[4] = f2bf(q.x); af[5] = f2bf(q.y); af[6] = f2bf(q.z); af[7] = f2bf(q.w);
            acc0 = __builtin_amdgcn_mfma_f32_32x32x16_bf16(af, bw[kk][0], acc0, 0, 0, 0);
            acc1 = __builtin_amdgcn_mfma_f32_32x32x16_bf16(af, bw[kk][1], acc1, 0, 0, 0);
        }

        #pragma unroll
        for (int r = 0; r < 16; ++r) {
            int node = base + (r & 3) + 8 * (r >> 2) + 4 * h;
            float dv = dinv[node];
            float v0 = acc0[r] * dv;
            float v1 = acc1[r] * dv;
            xws[node * NHID + l31] = v0;
            xws[node * NHID + 32 + l31] = v1;
            agg[node * NHID + l31] = v0;
            agg[node * NHID + 32 + l31] = v1;
        }
    }
}

// ---------------------------------------------------------------------------
// K4: agg[col] += w_e * xws[row].  One wave per edge, lane = feature.
// ---------------------------------------------------------------------------
__global__ __launch_bounds__(256) void k4_scatter(
    const float* __restrict__ edge_w, const int* __restrict__ eidx,
    const float* __restrict__ xws, float* __restrict__ agg) {
    int lane = threadIdx.x & 63;
    int wid = __builtin_amdgcn_readfirstlane(threadIdx.x >> 6);
    int e = blockIdx.x * 4 + wid;
    if (e >= N_EDGES) return;
    float w = edge_w[e];
    if (w <= 0.0f) return;
    int row = eidx[e];
    int col = eidx[N_EDGES + e];
    float v = w * xws[row * NHID + lane];
    atomicAdd(&agg[col * NHID + lane], v);
}

// ---------------------------------------------------------------------------
// K5: node = relu(dinv[n]*agg[n] + b_g); pooled[batch[n]] += node.
// ---------------------------------------------------------------------------
__global__ __launch_bounds__(64) void k5_pool(
    const float* __restrict__ agg, const float* __restrict__ dinv,
    const float* __restrict__ bg, const int* __restrict__ batch,
    float* __restrict__ pooled) {
    int lane = threadIdx.x;
    int n0 = blockIdx.x * 64;
    int n1 = min(n0 + 64, N_NODES);
    if (n0 >= N_NODES) return;
    float bgl = bg[lane];
    float acc = 0.0f;
    int cur = batch[n0];
    for (int n = n0; n < n1; ++n) {
        int g = batch[n];
        if (g != cur) {
            atomicAdd(&pooled[cur * NHID + lane], acc);
            acc = 0.0f;
            cur = g;
        }
        float v = fmaxf(dinv[n] * agg[n * NHID + lane] + bgl, 0.0f);
        acc += v;
    }
    atomicAdd(&pooled[cur * NHID + lane], acc);
}

// ---------------------------------------------------------------------------
// K6: z = relu(pooled @ W_b1 + b_b1); out = z @ W_b2 + b_b2.
// ---------------------------------------------------------------------------
__global__ __launch_bounds__(64) void k6_final(
    const float* __restrict__ pooled, const float* __restrict__ Wb1,
    const float* __restrict__ bb1, const float* __restrict__ Wb2,
    const float* __restrict__ bb2, float* __restrict__ out) {
    __shared__ float p[NHID];
    int lane = threadIdx.x;
    int g = blockIdx.x;
    p[lane] = pooled[g * NHID + lane];
    __syncthreads();
    float z = bb1[lane];
    #pragma unroll
    for (int k = 0; k < NHID; ++k) z += p[k] * Wb1[k * NHID + lane];
    z = fmaxf(z, 0.0f) * Wb2[lane];
    #pragma unroll
    for (int off = 32; off > 0; off >>= 1)
        z += __shfl_down(z, off, 64);
    if (lane == 0) out[g] = z + bb2[0];
}

// ---------------------------------------------------------------------------
extern "C" void kernel_launch(void* const* d_in, const int* in_sizes, int n_in,
                              void* d_out, int out_size, void* d_ws, size_t ws_size,
                              hipStream_t stream) {
    const float* x        = (const float*)d_in[0];
    const float* ea       = (const float*)d_in[1];
    const float* W_e1     = (const float*)d_in[2];
    const float* b_e1     = (const float*)d_in[3];
    const float* W_e2     = (const float*)d_in[4];
    const float* b_e2     = (const float*)d_in[5];
    const float* W_e3     = (const float*)d_in[6];
    const float* b_e3     = (const float*)d_in[7];
    const float* W_g      = (const float*)d_in[8];
    const float* b_g      = (const float*)d_in[9];
    const float* W_b1     = (const float*)d_in[10];
    const float* b_b1     = (const float*)d_in[11];
    const float* W_b2     = (const float*)d_in[12];
    const float* b_b2     = (const float*)d_in[13];
    const int*   eidx     = (const int*)d_in[14];
    const int*   batch    = (const int*)d_in[15];
    float* out = (float*)d_out;

    float* ws = (float*)d_ws;
    float* edge_w = ws;                         // 1,250,000
    float* deg    = ws + 1250048;               // 100,000 (becomes dinv in-place)
    float* xws    = ws + 1350080;               // 6,400,000
    float* agg    = ws + 7750080;               // 6,400,000
    float* pooled = ws + 14150080;              // 16,384

    k0_init<<<dim3((N_NODES + 255) / 256), dim3(256), 0, stream>>>(deg, pooled);
    k1_edge_mlp<<<dim3(1024), dim3(256), 0, stream>>>(
        ea, W_e1, b_e1, W_e2, b_e2, W_e3, b_e3, eidx, edge_w, deg);
    k2_rsqrt<<<dim3((N_NODES + 255) / 256), dim3(256), 0, stream>>>(deg);
    k3_xw<<<dim3(512), dim3(256), 0, stream>>>(x, W_g, deg, xws, agg);
    k4_scatter<<<dim3((N_EDGES + 3) / 4), dim3(256), 0, stream>>>(edge_w, eidx, xws, agg);
    k5_pool<<<dim3((N_NODES + 63) / 64), dim3(64), 0, stream>>>(agg, deg, b_g, batch, pooled);
    k6_final<<<dim3(NUM_GRAPHS), dim3(64), 0, stream>>>(pooled, W_b1, b_b1, W_b2, b_b2, out);
}

// Round 4
// 226.948 us; speedup vs baseline: 2.1817x; 1.3416x over previous
//
#include <hip/hip_runtime.h>
#include <hip/hip_bf16.h>

#define N_NODES 100000
#define N_EDGES 1250000
#define N_FEAT 128
#define NHID 64
#define NUM_GRAPHS 256
#define NB_SCAN 98   // 98*1024 >= 100000

typedef __attribute__((ext_vector_type(8))) short short8;
typedef __attribute__((ext_vector_type(16))) float float16;

static __device__ __forceinline__ short f2bf(float x) {
    __hip_bfloat16 b = __float2bfloat16(x);
    return *reinterpret_cast<short*>(&b);
}
static __device__ __forceinline__ float bf2f(short s) {
    __hip_bfloat16 b = *reinterpret_cast<__hip_bfloat16*>(&s);
    return __bfloat162float(b);
}

// ---------------------------------------------------------------------------
// K0: cnt = 0, pooled = 0
// ---------------------------------------------------------------------------
__global__ void k0_init(int* __restrict__ cnt, float* __restrict__ pooled) {
    int i = blockIdx.x * blockDim.x + threadIdx.x;
    if (i < N_NODES) cnt[i] = 0;
    if (i < NUM_GRAPHS * NHID) pooled[i] = 0.0f;
}

// ---------------------------------------------------------------------------
// K1: edge MLP, all-MFMA (one wave per 32 edges, grid-stride).
// Fused: edge_w store + int histogram cnt[col]++ for live edges.
// ---------------------------------------------------------------------------
__global__ __launch_bounds__(256) void k1_edge_mlp(
    const float* __restrict__ ea, const float* __restrict__ W1,
    const float* __restrict__ b1, const float* __restrict__ W2,
    const float* __restrict__ b2, const float* __restrict__ W3,
    const float* __restrict__ b3, const int* __restrict__ eidx,
    float* __restrict__ edge_w, int* __restrict__ cnt)
{
    const int lane = threadIdx.x & 63;
    const int l31 = lane & 31;
    const int h = lane >> 5;
    const int wslot = blockIdx.x * 4 + (threadIdx.x >> 6);
    const float b3v = b3[0];

    // layer1 A-frags: W1^T hi/lo. A[m=t*32+l31][k=8h+j] = W1[k][m], k<5.
    short8 a1hi[2], a1lo[2];
    #pragma unroll
    for (int t = 0; t < 2; ++t)
        #pragma unroll
        for (int j = 0; j < 8; ++j) {
            int k = 8 * h + j;
            float v = (k < 5) ? W1[k * NHID + t * 32 + l31] : 0.0f;
            short hi = f2bf(v);
            a1hi[t][j] = hi;
            a1lo[t][j] = f2bf(v - bf2f(hi));
        }

    float b1r[2][16];
    #pragma unroll
    for (int t = 0; t < 2; ++t)
        #pragma unroll
        for (int r = 0; r < 16; ++r)
            b1r[t][r] = b1[t * 32 + (r & 3) + 8 * (r >> 2) + 4 * h];

    short8 afrag[2][4];
    #pragma unroll
    for (int t = 0; t < 2; ++t)
        #pragma unroll
        for (int kk = 0; kk < 4; ++kk)
            #pragma unroll
            for (int j = 0; j < 8; ++j) {
                int k = kk * 16 + h * 8 + j;
                afrag[t][kk][j] = f2bf(W2[k * NHID + t * 32 + l31]);
            }

    float b2r[2][16], w3r[2][16];
    #pragma unroll
    for (int t = 0; t < 2; ++t)
        #pragma unroll
        for (int r = 0; r < 16; ++r) {
            int hid = t * 32 + (r & 3) + 8 * (r >> 2) + 4 * h;
            b2r[t][r] = b2[hid];
            w3r[t][r] = W3[hid];
        }

    const int NCHUNK = (N_EDGES + 31) / 32;
    for (int chunk = wslot; chunk < NCHUNK; chunk += gridDim.x * 4) {
        int e = chunk * 32 + l31;
        bool valid = e < N_EDGES;
        int ec = valid ? e : (N_EDGES - 1);

        short8 behi, belo;
        #pragma unroll
        for (int j = 0; j < 8; ++j) {
            float v = (h == 0 && j < 5) ? ea[ec * 5 + j] : 0.0f;
            short hi = f2bf(v);
            behi[j] = hi;
            belo[j] = f2bf(v - bf2f(hi));
        }

        float16 acc1a, acc1b;
        #pragma unroll
        for (int r = 0; r < 16; ++r) { acc1a[r] = b1r[0][r]; acc1b[r] = b1r[1][r]; }
        acc1a = __builtin_amdgcn_mfma_f32_32x32x16_bf16(a1hi[0], behi, acc1a, 0, 0, 0);
        acc1a = __builtin_amdgcn_mfma_f32_32x32x16_bf16(a1hi[0], belo, acc1a, 0, 0, 0);
        acc1a = __builtin_amdgcn_mfma_f32_32x32x16_bf16(a1lo[0], behi, acc1a, 0, 0, 0);
        acc1b = __builtin_amdgcn_mfma_f32_32x32x16_bf16(a1hi[1], behi, acc1b, 0, 0, 0);
        acc1b = __builtin_amdgcn_mfma_f32_32x32x16_bf16(a1hi[1], belo, acc1b, 0, 0, 0);
        acc1b = __builtin_amdgcn_mfma_f32_32x32x16_bf16(a1lo[1], behi, acc1b, 0, 0, 0);
        #pragma unroll
        for (int r = 0; r < 16; ++r) {
            acc1a[r] = fmaxf(acc1a[r], 0.0f);
            acc1b[r] = fmaxf(acc1b[r], 0.0f);
        }

        // exchange + pack into layer2 B-frags
        short8 bf2v[4];
        #pragma unroll
        for (int kk = 0; kk < 4; ++kk) {
            #pragma unroll
            for (int j2 = 0; j2 < 4; ++j2) {
                float lv, hv;
                if (kk >> 1) { lv = acc1b[j2 + 8 * (kk & 1)]; hv = acc1b[j2 + 8 * (kk & 1) + 4]; }
                else         { lv = acc1a[j2 + 8 * (kk & 1)]; hv = acc1a[j2 + 8 * (kk & 1) + 4]; }
                float send = h ? lv : hv;
                float recv = __shfl_xor(send, 32, 64);
                float jlo = h ? recv : lv;
                float jhi = h ? hv : recv;
                bf2v[kk][j2] = f2bf(jlo);
                bf2v[kk][4 + j2] = f2bf(jhi);
            }
        }

        float16 c0, c1;
        #pragma unroll
        for (int r = 0; r < 16; ++r) { c0[r] = b2r[0][r]; c1[r] = b2r[1][r]; }
        #pragma unroll
        for (int kk = 0; kk < 4; ++kk) {
            c0 = __builtin_amdgcn_mfma_f32_32x32x16_bf16(afrag[0][kk], bf2v[kk], c0, 0, 0, 0);
            c1 = __builtin_amdgcn_mfma_f32_32x32x16_bf16(afrag[1][kk], bf2v[kk], c1, 0, 0, 0);
        }

        float partial = 0.0f;
        #pragma unroll
        for (int r = 0; r < 16; ++r) {
            partial += fmaxf(c0[r], 0.0f) * w3r[0][r];
            partial += fmaxf(c1[r], 0.0f) * w3r[1][r];
        }
        float total = partial + __shfl_xor(partial, 32, 64);
        float w = fmaxf(total + b3v, 0.0f);

        if (h == 0 && valid) {
            edge_w[e] = w;
            if (w > 0.0f) atomicAdd(&cnt[eidx[N_EDGES + e]], 1);
        }
    }
}

// ---------------------------------------------------------------------------
// Scan: cnt[100000] -> exclusive offsets off[100001]; cur = off copy.
// ---------------------------------------------------------------------------
__global__ __launch_bounds__(1024) void s1_blocksum(const int* __restrict__ cnt,
                                                    int* __restrict__ bsum) {
    __shared__ int sd[1024];
    int t = threadIdx.x;
    int i = blockIdx.x * 1024 + t;
    sd[t] = (i < N_NODES) ? cnt[i] : 0;
    __syncthreads();
    #pragma unroll
    for (int d = 512; d > 0; d >>= 1) {
        if (t < d) sd[t] += sd[t + d];
        __syncthreads();
    }
    if (t == 0) bsum[blockIdx.x] = sd[0];
}

__global__ void s2_scanbase(const int* __restrict__ bsum, int* __restrict__ bbase,
                            int* __restrict__ off) {
    if (threadIdx.x == 0 && blockIdx.x == 0) {
        int run = 0;
        for (int b = 0; b < NB_SCAN; ++b) { bbase[b] = run; run += bsum[b]; }
        off[N_NODES] = run;
    }
}

__global__ __launch_bounds__(1024) void s3_blockscan(const int* __restrict__ cnt,
                                                     const int* __restrict__ bbase,
                                                     int* __restrict__ off,
                                                     int* __restrict__ cur) {
    __shared__ int sd[1024];
    int t = threadIdx.x;
    int i = blockIdx.x * 1024 + t;
    int c = (i < N_NODES) ? cnt[i] : 0;
    sd[t] = c;
    __syncthreads();
    #pragma unroll
    for (int d = 1; d < 1024; d <<= 1) {
        int v = (t >= d) ? sd[t - d] : 0;
        __syncthreads();
        sd[t] += v;
        __syncthreads();
    }
    if (i < N_NODES) {
        int ex = sd[t] - c + bbase[blockIdx.x];
        off[i] = ex;
        cur[i] = ex;
    }
}

// ---------------------------------------------------------------------------
// K_place: scatter live edges into CSR slots (packed {row, w} int2).
// ---------------------------------------------------------------------------
__global__ void k_place(const float* __restrict__ edge_w, const int* __restrict__ eidx,
                        int* __restrict__ cur, int2* __restrict__ recs) {
    int e = blockIdx.x * 256 + threadIdx.x;
    if (e >= N_EDGES) return;
    float w = edge_w[e];
    if (w <= 0.0f) return;
    int col = eidx[N_EDGES + e];
    int pos = atomicAdd(&cur[col], 1);
    recs[pos] = make_int2(eidx[e], __float_as_int(w));
}

// ---------------------------------------------------------------------------
// K_deg: dinv[n] = rsqrt(1 + sum of w over n's in-segment). Contiguous reads.
// ---------------------------------------------------------------------------
__global__ void k_deg(const int* __restrict__ off, const int2* __restrict__ recs,
                      float* __restrict__ dinv) {
    int n = blockIdx.x * 256 + threadIdx.x;
    if (n >= N_NODES) return;
    int o0 = off[n], o1 = off[n + 1];
    float s = 1.0f;
    for (int j = o0; j < o1; ++j) s += __int_as_float(recs[j].y);
    dinv[n] = rsqrtf(s);
}

// ---------------------------------------------------------------------------
// K3: xws[n] = dinv[n]*(x[n]@Wg) via MFMA; one wave per 32 nodes.
// ---------------------------------------------------------------------------
__global__ __launch_bounds__(256) void k3_xw(
    const float* __restrict__ x, const float* __restrict__ Wg,
    const float* __restrict__ dinv, float* __restrict__ xws)
{
    const int lane = threadIdx.x & 63;
    const int l31 = lane & 31;
    const int h = lane >> 5;
    const int wslot = blockIdx.x * 4 + (threadIdx.x >> 6);

    short8 bw[8][2];
    #pragma unroll
    for (int kk = 0; kk < 8; ++kk)
        #pragma unroll
        for (int u = 0; u < 2; ++u)
            #pragma unroll
            for (int j = 0; j < 8; ++j)
                bw[kk][u][j] = f2bf(Wg[(kk * 16 + 8 * h + j) * NHID + u * 32 + l31]);

    const int NC = N_NODES / 32;
    for (int chunk = wslot; chunk < NC; chunk += gridDim.x * 4) {
        int base = chunk * 32;
        const float* xrow = x + (size_t)(base + l31) * N_FEAT + 8 * h;

        float16 acc0, acc1;
        #pragma unroll
        for (int r = 0; r < 16; ++r) { acc0[r] = 0.0f; acc1[r] = 0.0f; }

        #pragma unroll
        for (int kk = 0; kk < 8; ++kk) {
            float4 p = *(const float4*)(xrow + kk * 16);
            float4 q = *(const float4*)(xrow + kk * 16 + 4);
            short8 af;
            af[0] = f2bf(p.x); af[1] = f2bf(p.y); af[2] = f2bf(p.z); af[3] = f2bf(p.w);
            af[4] = f2bf(q.x); af[5] = f2bf(q.y); af[6] = f2bf(q.z); af[7] = f2bf(q.w);
            acc0 = __builtin_amdgcn_mfma_f32_32x32x16_bf16(af, bw[kk][0], acc0, 0, 0, 0);
            acc1 = __builtin_amdgcn_mfma_f32_32x32x16_bf16(af, bw[kk][1], acc1, 0, 0, 0);
        }

        #pragma unroll
        for (int r = 0; r < 16; ++r) {
            int node = base + (r & 3) + 8 * (r >> 2) + 4 * h;
            float dv = dinv[node];
            xws[node * NHID + l31] = acc0[r] * dv;
            xws[node * NHID + 32 + l31] = acc1[r] * dv;
        }
    }
}

// ---------------------------------------------------------------------------
// K4: fused gather + relu + pool. One wave per 8 consecutive nodes.
// acc init = xws[n] (self-loop); software-pipelined rec->gather loop;
// pooled flushed on graph-id change (batch sorted).
// ---------------------------------------------------------------------------
__global__ __launch_bounds__(256) void k4_gather_pool(
    const int* __restrict__ off, const int2* __restrict__ recs,
    const float* __restrict__ xws, const float* __restrict__ dinv,
    const float* __restrict__ bg, const int* __restrict__ batch,
    float* __restrict__ pooled)
{
    const int lane = threadIdx.x & 63;
    const int wv = blockIdx.x * 4 + (threadIdx.x >> 6);
    int n0 = wv * 8;
    if (n0 >= N_NODES) return;
    float bgl = bg[lane];
    float pacc = 0.0f;
    int curg = batch[n0];
    #pragma unroll
    for (int nn = 0; nn < 8; ++nn) {
        int n = n0 + nn;
        int g = batch[n];
        if (g != curg) {
            atomicAdd(&pooled[curg * NHID + lane], pacc);
            pacc = 0.0f;
            curg = g;
        }
        int o0 = off[n], o1 = off[n + 1];
        float acc = xws[(size_t)n * NHID + lane];
        if (o0 < o1) {
            int2 r = recs[o0];
            float gth = xws[(size_t)r.x * NHID + lane];
            for (int j = o0; j < o1 - 1; ++j) {
                int2 rn = recs[j + 1];                       // prefetch next rec
                float gn = xws[(size_t)rn.x * NHID + lane];  // issue next gather
                acc = fmaf(__int_as_float(r.y), gth, acc);
                r = rn; gth = gn;
            }
            acc = fmaf(__int_as_float(r.y), gth, acc);
        }
        pacc += fmaxf(dinv[n] * acc + bgl, 0.0f);
    }
    atomicAdd(&pooled[curg * NHID + lane], pacc);
}

// ---------------------------------------------------------------------------
// K6: z = relu(pooled @ W_b1 + b_b1); out = z @ W_b2 + b_b2.
// ---------------------------------------------------------------------------
__global__ __launch_bounds__(64) void k6_final(
    const float* __restrict__ pooled, const float* __restrict__ Wb1,
    const float* __restrict__ bb1, const float* __restrict__ Wb2,
    const float* __restrict__ bb2, float* __restrict__ out) {
    __shared__ float p[NHID];
    int lane = threadIdx.x;
    int g = blockIdx.x;
    p[lane] = pooled[g * NHID + lane];
    __syncthreads();
    float z = bb1[lane];
    #pragma unroll
    for (int k = 0; k < NHID; ++k) z += p[k] * Wb1[k * NHID + lane];
    z = fmaxf(z, 0.0f) * Wb2[lane];
    #pragma unroll
    for (int off = 32; off > 0; off >>= 1)
        z += __shfl_down(z, off, 64);
    if (lane == 0) out[g] = z + bb2[0];
}

// ---------------------------------------------------------------------------
extern "C" void kernel_launch(void* const* d_in, const int* in_sizes, int n_in,
                              void* d_out, int out_size, void* d_ws, size_t ws_size,
                              hipStream_t stream) {
    const float* x        = (const float*)d_in[0];
    const float* ea       = (const float*)d_in[1];
    const float* W_e1     = (const float*)d_in[2];
    const float* b_e1     = (const float*)d_in[3];
    const float* W_e2     = (const float*)d_in[4];
    const float* b_e2     = (const float*)d_in[5];
    const float* W_e3     = (const float*)d_in[6];
    const float* b_e3     = (const float*)d_in[7];
    const float* W_g      = (const float*)d_in[8];
    const float* b_g      = (const float*)d_in[9];
    const float* W_b1     = (const float*)d_in[10];
    const float* b_b1     = (const float*)d_in[11];
    const float* W_b2     = (const float*)d_in[12];
    const float* b_b2     = (const float*)d_in[13];
    const int*   eidx     = (const int*)d_in[14];
    const int*   batch    = (const int*)d_in[15];
    float* out = (float*)d_out;

    // workspace layout (4-byte units); recs 8B-aligned. Total ~42.3 MB.
    char* wsb = (char*)d_ws;
    float* edge_w = (float*)wsb;                        // 1,250,000 f
    int*   cnt    = (int*)(wsb + 4 * 1250048);          // 100,000 i
    int*   off    = (int*)(wsb + 4 * 1350080);          // 100,001 i
    int*   cur    = (int*)(wsb + 4 * 1450112);          // 100,000 i
    int*   bsum   = (int*)(wsb + 4 * 1550144);          // 98 i
    int*   bbase  = (int*)(wsb + 4 * 1550272);          // 98 i
    float* dinv   = (float*)(wsb + 4 * 1550400);        // 100,000 f
    float* pooled = (float*)(wsb + 4 * 1650432);        // 16,384 f
    int2*  recs   = (int2*)(wsb + 4 * 1666880);         // up to 1,250,000 int2
    float* xws    = (float*)(wsb + 4 * 4166880);        // 6,400,000 f

    k0_init<<<dim3(391), dim3(256), 0, stream>>>(cnt, pooled);
    k1_edge_mlp<<<dim3(1024), dim3(256), 0, stream>>>(
        ea, W_e1, b_e1, W_e2, b_e2, W_e3, b_e3, eidx, edge_w, cnt);
    s1_blocksum<<<dim3(NB_SCAN), dim3(1024), 0, stream>>>(cnt, bsum);
    s2_scanbase<<<dim3(1), dim3(64), 0, stream>>>(bsum, bbase, off);
    s3_blockscan<<<dim3(NB_SCAN), dim3(1024), 0, stream>>>(cnt, bbase, off, cur);
    k_place<<<dim3((N_EDGES + 255) / 256), dim3(256), 0, stream>>>(edge_w, eidx, cur, recs);
    k_deg<<<dim3((N_NODES + 255) / 256), dim3(256), 0, stream>>>(off, recs, dinv);
    k3_xw<<<dim3(512), dim3(256), 0, stream>>>(x, W_g, dinv, xws);
    k4_gather_pool<<<dim3(3125), dim3(256), 0, stream>>>(off, recs, xws, dinv, b_g, batch, pooled);
    k6_final<<<dim3(NUM_GRAPHS), dim3(64), 0, stream>>>(pooled, W_b1, b_b1, W_b2, b_b2, out);
}